// Round 1
// baseline (506.902 us; speedup 1.0000x reference)
//
#include <hip/hip_runtime.h>
#include <hip/hip_bf16.h>

typedef __attribute__((ext_vector_type(4))) float  f32x4;
typedef __attribute__((ext_vector_type(8))) short  s16x8;
typedef __attribute__((ext_vector_type(4))) short  s16x4;

union BH4 { s16x4 v; __hip_bfloat16 h[4]; };
union BH8 { s16x8 v; __hip_bfloat16 h[8]; };

#define MFMA16(A,B,C) __builtin_amdgcn_mfma_f32_16x16x32_bf16((A),(B),(C),0,0,0)

// X buffer: [256 rows][256 d] bf16, 512 B/row; XOR-swizzle 16B slots by row to
// break the 512B-stride bank conflict on A-fragment ds_read_b128.
__device__ __forceinline__ int xaddr(int row, int byteInRow) {
  return ((row << 9) + byteInRow) ^ ((row & 7) << 4);
}
// chunk buffers: [256 i][32 k] bf16 (64 B/row); swizzle the 16B k-slot by i so
// 16 consecutive i land on distinct bank quads.
__device__ __forceinline__ int caddr(int i, int k) {
  return (i << 6) + ((((k >> 3) ^ ((i >> 1) & 3)) << 4) + ((k & 7) << 1));
}
__device__ __forceinline__ float sigm(float x) { return 1.0f / (1.0f + __expf(-x)); }

// Reorder fp32 weight [256][256] into bf16 MFMA B-fragment order:
// dst[((ct*8+ks)*64+lane)*8 + j] = w[ct*16 + (lane&15)][ks*32 + (lane>>4)*8 + j]
__global__ void wfrag_kernel(const float* __restrict__ w_in,
                             const float* __restrict__ w_gate,
                             const float* __restrict__ w_out,
                             __hip_bfloat16* __restrict__ dst) {
  const int lane = threadIdx.x;         // 64
  const int fid  = blockIdx.x;          // 0..127 = ct*8+ks
  const int m    = blockIdx.y;          // 0:wa 1:wb 2:wg 3:wo
  const float* src = (m == 0) ? w_in : (m == 1) ? (w_in + 65536)
                    : (m == 2) ? w_gate : w_out;
  const int e  = (fid >> 3) * 16 + (lane & 15);
  const int d0 = (fid & 7) * 32 + (lane >> 4) * 8;
  BH8 u;
  #pragma unroll
  for (int j = 0; j < 8; ++j) u.h[j] = __float2bfloat16(src[e * 256 + d0 + j]);
  *reinterpret_cast<s16x8*>(dst + (size_t)m * 65536 + ((size_t)fid * 64 + lane) * 8) = u.v;
}

__global__ __launch_bounds__(512, 2) void tri_fused(
    const float* __restrict__ pair,
    const __hip_bfloat16* __restrict__ wfrag,
    const float* __restrict__ gamma,
    const float* __restrict__ beta,
    float* __restrict__ out)
{
  extern __shared__ __align__(16) char lds[];
  char* const Xb  = lds;            // 131072 B : x, later ln(tri)  [256][256] bf16 swz
  char* const aTb = lds + 131072;   // 16384 B  : a^T chunk [256 i][32 k] bf16 swz
  char* const bTb = lds + 147456;   // 16384 B  : b^T chunk

  const int tid  = threadIdx.x;
  const int lane = tid & 63;
  const int w    = tid >> 6;        // wave 0..7
  const int l15  = lane & 15;
  const int lh   = lane >> 4;       // 0..3
  const size_t sbase = (size_t)blockIdx.x * 65536;  // slice base (elements)

  const __hip_bfloat16* const wa = wfrag;
  const __hip_bfloat16* const wb = wfrag + 65536;
  const __hip_bfloat16* const wg = wfrag + 131072;
  const __hip_bfloat16* const wo = wfrag + 196608;

  // ---------- phase 0: x = LN(pair_slice) -> Xb (bf16) ----------
  {
    const int d0 = lane * 4;
    const float4 gm = *reinterpret_cast<const float4*>(gamma + d0);
    const float4 bt = *reinterpret_cast<const float4*>(beta  + d0);
    const int r0 = w * 32;
    for (int rr = 0; rr < 32; ++rr) {
      const int r = r0 + rr;
      float4 v = *reinterpret_cast<const float4*>(pair + sbase + (size_t)r * 256 + d0);
      float s  = v.x + v.y + v.z + v.w;
      float ss = v.x*v.x + v.y*v.y + v.z*v.z + v.w*v.w;
      #pragma unroll
      for (int m = 1; m < 64; m <<= 1) { s += __shfl_xor(s, m); ss += __shfl_xor(ss, m); }
      const float mean = s * (1.0f/256.0f);
      const float rstd = rsqrtf(ss * (1.0f/256.0f) - mean*mean + 1e-5f);
      BH4 o;
      o.h[0] = __float2bfloat16((v.x - mean) * rstd * gm.x + bt.x);
      o.h[1] = __float2bfloat16((v.y - mean) * rstd * gm.y + bt.y);
      o.h[2] = __float2bfloat16((v.z - mean) * rstd * gm.z + bt.z);
      o.h[3] = __float2bfloat16((v.w - mean) * rstd * gm.w + bt.w);
      *reinterpret_cast<s16x4*>(Xb + xaddr(r, d0 * 2)) = o.v;
    }
  }
  __syncthreads();

  // ---------- phase 1: g = sigmoid(x @ Wg^T), register-resident bf16 ----------
  // column-split: wave w handles output cols ct = 2w, 2w+1 (all 256 rows)
  s16x4 g_pk[2][16];
  {
    #pragma unroll
    for (int cc = 0; cc < 2; ++cc) {
      const int ct = w * 2 + cc;
      s16x8 bfr[8];
      #pragma unroll
      for (int ks = 0; ks < 8; ++ks)
        bfr[ks] = *reinterpret_cast<const s16x8*>(wg + (((size_t)ct * 8 + ks) * 64 + lane) * 8);
      #pragma unroll
      for (int rt0 = 0; rt0 < 16; rt0 += 4) {
        f32x4 acc[4];
        #pragma unroll
        for (int u = 0; u < 4; ++u) acc[u] = (f32x4){0.f,0.f,0.f,0.f};
        #pragma unroll
        for (int ks = 0; ks < 8; ++ks) {
          #pragma unroll
          for (int u = 0; u < 4; ++u) {
            const s16x8 afr = *reinterpret_cast<const s16x8*>(
                Xb + xaddr((rt0 + u) * 16 + l15, ks * 64 + lh * 16));
            acc[u] = MFMA16(afr, bfr[ks], acc[u]);
          }
        }
        #pragma unroll
        for (int u = 0; u < 4; ++u) {
          BH4 o;
          #pragma unroll
          for (int q = 0; q < 4; ++q) o.h[q] = __float2bfloat16(sigm(acc[u][q]));
          g_pk[cc][rt0 + u] = o.v;
        }
      }
    }
  }

  // ---------- phase 2: tri = a^T b accumulated over 8 k-chunks of 32 ----------
  // row-split: wave w owns tri rows [32w, 32w+32), all 256 cols.
  f32x4 tri[2][16];
  #pragma unroll
  for (int rt = 0; rt < 2; ++rt)
    #pragma unroll
    for (int ct = 0; ct < 16; ++ct) tri[rt][ct] = (f32x4){0.f,0.f,0.f,0.f};

  const __hip_bfloat16* const wab = (w < 4) ? wa : wb;
  char* const mychunk = (w < 4) ? aTb : bTb;
  const int ctbase = (w & 3) * 4;

  for (int c = 0; c < 8; ++c) {
    __syncthreads();   // previous tri-accum done before overwriting chunk bufs
    // chunk GEMM: rows k = c*32..c*32+31 of x; this wave does 4 col-tiles of a (w<4) or b
    #pragma unroll
    for (int half = 0; half < 2; ++half) {
      f32x4 acc[4];    // [c2][rt]
      #pragma unroll
      for (int t = 0; t < 4; ++t) acc[t] = (f32x4){0.f,0.f,0.f,0.f};
      #pragma unroll
      for (int ks = 0; ks < 8; ++ks) {
        const s16x8 a0 = *reinterpret_cast<const s16x8*>(Xb + xaddr(c*32 +      l15, ks*64 + lh*16));
        const s16x8 a1 = *reinterpret_cast<const s16x8*>(Xb + xaddr(c*32 + 16 + l15, ks*64 + lh*16));
        #pragma unroll
        for (int c2 = 0; c2 < 2; ++c2) {
          const int ct = ctbase + half * 2 + c2;
          const s16x8 bfr = *reinterpret_cast<const s16x8*>(
              wab + (((size_t)ct * 8 + ks) * 64 + lane) * 8);
          acc[c2*2]     = MFMA16(a0, bfr, acc[c2*2]);
          acc[c2*2 + 1] = MFMA16(a1, bfr, acc[c2*2 + 1]);
        }
      }
      // SiLU + transposed store into chunk buffer: [i=channel][k=local row]
      #pragma unroll
      for (int c2 = 0; c2 < 2; ++c2) {
        const int i = (ctbase + half*2 + c2) * 16 + l15;
        #pragma unroll
        for (int rt = 0; rt < 2; ++rt) {
          const f32x4 v = acc[c2*2 + rt];
          BH4 o;
          #pragma unroll
          for (int q = 0; q < 4; ++q) o.h[q] = __float2bfloat16(v[q] * sigm(v[q]));
          *reinterpret_cast<s16x4*>(mychunk + caddr(i, rt*16 + lh*4)) = o.v;
        }
      }
    }
    __syncthreads();   // chunk bufs ready
    // tri accumulation: one K=32 MFMA step per 16x16 tile
    const s16x8 ta0 = *reinterpret_cast<const s16x8*>(aTb + caddr(w*32 +      l15, lh*8));
    const s16x8 ta1 = *reinterpret_cast<const s16x8*>(aTb + caddr(w*32 + 16 + l15, lh*8));
    #pragma unroll
    for (int ct = 0; ct < 16; ++ct) {
      const s16x8 tb = *reinterpret_cast<const s16x8*>(bTb + caddr(ct*16 + l15, lh*8));
      tri[0][ct] = MFMA16(ta0, tb, tri[0][ct]);
      tri[1][ct] = MFMA16(ta1, tb, tri[1][ct]);
    }
  }

  // ---------- phase 3: LN(tri) -> Xb (bf16), fully in-wave stats ----------
  {
    float gmr[16], btr[16];
    #pragma unroll
    for (int ct = 0; ct < 16; ++ct) {
      gmr[ct] = gamma[ct*16 + l15];
      btr[ct] = beta [ct*16 + l15];
    }
    #pragma unroll
    for (int rt = 0; rt < 2; ++rt) {
      #pragma unroll
      for (int q = 0; q < 4; ++q) {
        float s = 0.f, ss = 0.f;
        #pragma unroll
        for (int ct = 0; ct < 16; ++ct) { const float v = tri[rt][ct][q]; s += v; ss += v*v; }
        #pragma unroll
        for (int m = 1; m < 16; m <<= 1) { s += __shfl_xor(s, m); ss += __shfl_xor(ss, m); }
        const float mean = s * (1.0f/256.0f);
        const float rstd = rsqrtf(ss * (1.0f/256.0f) - mean*mean + 1e-5f);
        const int i = w*32 + rt*16 + lh*4 + q;
        #pragma unroll
        for (int ct = 0; ct < 16; ++ct) {
          const float v = (tri[rt][ct][q] - mean) * rstd * gmr[ct] + btr[ct];
          *reinterpret_cast<__hip_bfloat16*>(Xb + xaddr(i, (ct*16 + l15) * 2)) =
              __float2bfloat16(v);
        }
      }
    }
  }
  __syncthreads();

  // ---------- phase 4: out = (LN(tri) @ Wo^T) * g ----------
  {
    #pragma unroll
    for (int cc = 0; cc < 2; ++cc) {
      const int ct = w * 2 + cc;
      const int e  = ct * 16 + l15;
      s16x8 bfr[8];
      #pragma unroll
      for (int ks = 0; ks < 8; ++ks)
        bfr[ks] = *reinterpret_cast<const s16x8*>(wo + (((size_t)ct * 8 + ks) * 64 + lane) * 8);
      #pragma unroll
      for (int rt0 = 0; rt0 < 16; rt0 += 4) {
        f32x4 acc[4];
        #pragma unroll
        for (int u = 0; u < 4; ++u) acc[u] = (f32x4){0.f,0.f,0.f,0.f};
        #pragma unroll
        for (int ks = 0; ks < 8; ++ks) {
          #pragma unroll
          for (int u = 0; u < 4; ++u) {
            const s16x8 afr = *reinterpret_cast<const s16x8*>(
                Xb + xaddr((rt0 + u) * 16 + l15, ks * 64 + lh * 16));
            acc[u] = MFMA16(afr, bfr[ks], acc[u]);
          }
        }
        #pragma unroll
        for (int u = 0; u < 4; ++u) {
          const int i0 = (rt0 + u) * 16 + lh * 4;
          BH4 gv; gv.v = g_pk[cc][rt0 + u];
          #pragma unroll
          for (int q = 0; q < 4; ++q)
            out[sbase + (size_t)(i0 + q) * 256 + e] = acc[u][q] * __bfloat162float(gv.h[q]);
        }
      }
    }
  }
}

extern "C" void kernel_launch(void* const* d_in, const int* in_sizes, int n_in,
                              void* d_out, int out_size, void* d_ws, size_t ws_size,
                              hipStream_t stream) {
  const float* pair   = (const float*)d_in[0];
  const float* w_in   = (const float*)d_in[1];
  const float* w_gate = (const float*)d_in[2];
  const float* w_out  = (const float*)d_in[3];
  const float* gamma  = (const float*)d_in[4];
  const float* beta   = (const float*)d_in[5];
  float* out = (float*)d_out;
  __hip_bfloat16* wfrag = (__hip_bfloat16*)d_ws;   // 4 * 65536 bf16 = 512 KB

  (void)in_sizes; (void)n_in; (void)out_size; (void)ws_size;

  hipFuncSetAttribute(reinterpret_cast<const void*>(tri_fused),
                      hipFuncAttributeMaxDynamicSharedMemorySize, 163840);

  wfrag_kernel<<<dim3(128, 4), 64, 0, stream>>>(w_in, w_gate, w_out, wfrag);
  tri_fused<<<512, 512, 163840, stream>>>(pair, wfrag, gamma, beta, out);
}

// Round 2
// 467.388 us; speedup vs baseline: 1.0845x; 1.0845x over previous
//
#include <hip/hip_runtime.h>
#include <hip/hip_bf16.h>

typedef __attribute__((ext_vector_type(4))) float  f32x4;
typedef __attribute__((ext_vector_type(8))) short  s16x8;
typedef __attribute__((ext_vector_type(4))) short  s16x4;

union BH4 { s16x4 v; __hip_bfloat16 h[4]; };
union BH8 { s16x8 v; __hip_bfloat16 h[8]; };

#define MFMA16(A,B,C) __builtin_amdgcn_mfma_f32_16x16x32_bf16((A),(B),(C),0,0,0)

__device__ __forceinline__ float sigm(float x) { return 1.0f / (1.0f + __expf(-x)); }

// swizzled byte addr in a [rows][256] bf16 buffer (512 B rows): XOR row into 16B slot
__device__ __forceinline__ int xad(int r, int byteInRow) {
  return ((r << 9) + byteInRow) ^ ((r & 7) << 4);
}
// swizzled byte addr in a [rows][32] bf16 buffer (64 B rows)
__device__ __forceinline__ int cad(int i, int k) {   // k = bf16 index 0..31
  return (i << 6) + ((((k >> 3) ^ (i & 3)) << 4) | ((k & 7) << 1));
}

// Reorder fp32 weight [256][256] into bf16 MFMA B-fragment order:
// dst[((ct*8+ks)*64+lane)*8 + j] = w[ct*16 + (lane&15)][ks*32 + (lane>>4)*8 + j]
__global__ void wfrag_kernel(const float* __restrict__ w_in,
                             const float* __restrict__ w_gate,
                             const float* __restrict__ w_out,
                             __hip_bfloat16* __restrict__ dst) {
  const int lane = threadIdx.x;         // 64
  const int fid  = blockIdx.x;          // 0..127 = ct*8+ks
  const int m    = blockIdx.y;          // 0:wa 1:wb 2:wg 3:wo
  const float* src = (m == 0) ? w_in : (m == 1) ? (w_in + 65536)
                    : (m == 2) ? w_gate : w_out;
  const int e  = (fid >> 3) * 16 + (lane & 15);
  const int d0 = (fid & 7) * 32 + (lane >> 4) * 8;
  BH8 u;
  #pragma unroll
  for (int j = 0; j < 8; ++j) u.h[j] = __float2bfloat16(src[e * 256 + d0 + j]);
  *reinterpret_cast<s16x8*>(dst + (size_t)m * 65536 + ((size_t)fid * 64 + lane) * 8) = u.v;
}

// K1: x = LN(pair) -> ws, stored in A-fragment order:
// xws[((s*16+rt)*8+ks)*512 + lane*8 + j] = x[s][rt*16 + (lane&15)][ks*32 + (lane>>4)*8 + j]
__global__ __launch_bounds__(256) void ln_kernel(
    const float* __restrict__ pair, const float* __restrict__ gamma,
    const float* __restrict__ beta, __hip_bfloat16* __restrict__ xws)
{
  __shared__ char Xl[8192];
  const int t  = threadIdx.x;
  const int s  = blockIdx.x >> 4;
  const int rt = blockIdx.x & 15;
  const int r  = t >> 4;                 // local row 0..15
  const int c0 = (t & 15) * 16;
  const float* src = pair + (((size_t)s * 256 + rt * 16 + r) * 256 + c0);
  float v[16];
  #pragma unroll
  for (int i = 0; i < 4; ++i) {
    const float4 f = *reinterpret_cast<const float4*>(src + i * 4);
    v[i*4+0]=f.x; v[i*4+1]=f.y; v[i*4+2]=f.z; v[i*4+3]=f.w;
  }
  float sm = 0.f, ss = 0.f;
  #pragma unroll
  for (int i = 0; i < 16; ++i) { sm += v[i]; ss += v[i]*v[i]; }
  #pragma unroll
  for (int m = 1; m < 16; m <<= 1) { sm += __shfl_xor(sm, m); ss += __shfl_xor(ss, m); }
  const float mean = sm * (1.f/256.f);
  const float rstd = rsqrtf(ss * (1.f/256.f) - mean*mean + 1e-5f);
  #pragma unroll
  for (int i = 0; i < 4; ++i) {
    const float4 gm = *reinterpret_cast<const float4*>(gamma + c0 + i*4);
    const float4 bt = *reinterpret_cast<const float4*>(beta  + c0 + i*4);
    BH4 o;
    o.h[0] = __float2bfloat16((v[i*4+0]-mean)*rstd*gm.x + bt.x);
    o.h[1] = __float2bfloat16((v[i*4+1]-mean)*rstd*gm.y + bt.y);
    o.h[2] = __float2bfloat16((v[i*4+2]-mean)*rstd*gm.z + bt.z);
    o.h[3] = __float2bfloat16((v[i*4+3]-mean)*rstd*gm.w + bt.w);
    *reinterpret_cast<s16x4*>(Xl + xad(r, (c0 + i*4)*2)) = o.v;
  }
  __syncthreads();
  #pragma unroll
  for (int p = 0; p < 2; ++p) {
    const int u  = t + p * 256;
    const int ks = u >> 6;
    const int lp = u & 63;
    const s16x8 f = *reinterpret_cast<const s16x8*>(
        Xl + xad(lp & 15, ks*64 + ((lp>>4)&3)*16));
    *reinterpret_cast<s16x8*>(xws + ((((size_t)s*16 + rt)*8 + ks)*64 + lp)*8) = f;
  }
}

// K2: per half-slice block: a/b chunk GEMMs -> tri -> LN -> (out GEMM * recomputed g)
__global__ __launch_bounds__(512, 4) void tri_fused(
    const __hip_bfloat16* __restrict__ xws,
    const __hip_bfloat16* __restrict__ wfrag,
    const float* __restrict__ gamma, const float* __restrict__ beta,
    float* __restrict__ out)
{
  __shared__ char lds[65536];
  char* const Ac = lds;            // [128][32] bf16 swz, 8 KB (a^T chunk, block's half)
  char* const Bc = lds + 8192;     // [256][32] bf16 swz, 16 KB (b^T chunk, full)

  const int raw = blockIdx.x;                       // sibling halves -> same XCD
  const int L   = (raw & 7) * 128 + (raw >> 3);
  const int s   = L >> 1;
  const int h   = L & 1;

  const int tid = threadIdx.x, lane = tid & 63, w = tid >> 6;
  const int l15 = lane & 15, lh = lane >> 4;        // 0..3

  const __hip_bfloat16* const wa = wfrag;
  const __hip_bfloat16* const wb = wfrag + 65536;
  const __hip_bfloat16* const wg = wfrag + 131072;
  const __hip_bfloat16* const wo = wfrag + 196608;

  const __hip_bfloat16* const xs = xws + (size_t)s * 65536;   // slice x-frag base
  const int act = h * 8 + w;                                   // this wave's a col-tile

  f32x4 tri[16];                                   // wave's 16 tri rows x 256 cols
  #pragma unroll
  for (int ct = 0; ct < 16; ++ct) tri[ct] = (f32x4){0.f,0.f,0.f,0.f};

  for (int c = 0; c < 8; ++c) {
    // ---- chunk GEMM (global reads only): a ct=act, b ct={2w,2w+1}, rows 32c..32c+31
    f32x4 acc[6];
    #pragma unroll
    for (int i = 0; i < 6; ++i) acc[i] = (f32x4){0.f,0.f,0.f,0.f};
    #pragma unroll
    for (int ks = 0; ks < 8; ++ks) {
      const s16x8 A0  = *reinterpret_cast<const s16x8*>(xs + (((2*c  )*8 + ks)*64 + lane)*8);
      const s16x8 A1  = *reinterpret_cast<const s16x8*>(xs + (((2*c+1)*8 + ks)*64 + lane)*8);
      const s16x8 Ba  = *reinterpret_cast<const s16x8*>(wa + (((size_t)act*8     + ks)*64 + lane)*8);
      const s16x8 Bb0 = *reinterpret_cast<const s16x8*>(wb + (((size_t)(2*w)*8   + ks)*64 + lane)*8);
      const s16x8 Bb1 = *reinterpret_cast<const s16x8*>(wb + (((size_t)(2*w+1)*8 + ks)*64 + lane)*8);
      acc[0] = MFMA16(A0, Ba , acc[0]);
      acc[1] = MFMA16(A1, Ba , acc[1]);
      acc[2] = MFMA16(A0, Bb0, acc[2]);
      acc[3] = MFMA16(A1, Bb0, acc[3]);
      acc[4] = MFMA16(A0, Bb1, acc[4]);
      acc[5] = MFMA16(A1, Bb1, acc[5]);
    }
    __syncthreads();   // prior tri-accum LDS reads done before overwrite
    #pragma unroll
    for (int rt = 0; rt < 2; ++rt) {
      const int k0 = rt*16 + lh*4;     // chunk-local k of this lane's 4 values
      {
        const f32x4 vv = acc[rt];      // a, SiLU
        BH4 o;
        #pragma unroll
        for (int q = 0; q < 4; ++q) o.h[q] = __float2bfloat16(vv[q] * sigm(vv[q]));
        *reinterpret_cast<s16x4*>(Ac + cad(w*16 + l15, k0)) = o.v;
      }
      {
        const f32x4 vv = acc[2+rt];    // b ct=2w, SiLU
        BH4 o;
        #pragma unroll
        for (int q = 0; q < 4; ++q) o.h[q] = __float2bfloat16(vv[q] * sigm(vv[q]));
        *reinterpret_cast<s16x4*>(Bc + cad((2*w)*16 + l15, k0)) = o.v;
      }
      {
        const f32x4 vv = acc[4+rt];    // b ct=2w+1, SiLU
        BH4 o;
        #pragma unroll
        for (int q = 0; q < 4; ++q) o.h[q] = __float2bfloat16(vv[q] * sigm(vv[q]));
        *reinterpret_cast<s16x4*>(Bc + cad((2*w+1)*16 + l15, k0)) = o.v;
      }
    }
    __syncthreads();   // chunk buffers ready
    // ---- tri accumulation: tri[i][j] += sum_k aT[i][k] bT[j][k], K=32
    const s16x8 ta = *reinterpret_cast<const s16x8*>(Ac + cad(w*16 + l15, lh*8));
    #pragma unroll
    for (int ct = 0; ct < 16; ++ct) {
      const s16x8 tb = *reinterpret_cast<const s16x8*>(Bc + cad(ct*16 + l15, lh*8));
      tri[ct] = MFMA16(ta, tb, tri[ct]);
    }
  }
  __syncthreads();     // chunk bufs dead; reuse all LDS for lntri staging

  // ---- LN(tri), in-wave stats (row = lh*4+q, cols spread over ct,l15)
  float gr[16], br[16];
  #pragma unroll
  for (int ct = 0; ct < 16; ++ct) { gr[ct] = gamma[ct*16 + l15]; br[ct] = beta[ct*16 + l15]; }
  float mean[4], rstd[4];
  #pragma unroll
  for (int q = 0; q < 4; ++q) {
    float sm = 0.f, ss = 0.f;
    #pragma unroll
    for (int ct = 0; ct < 16; ++ct) { const float x = tri[ct][q]; sm += x; ss += x*x; }
    #pragma unroll
    for (int m = 1; m < 16; m <<= 1) { sm += __shfl_xor(sm, m); ss += __shfl_xor(ss, m); }
    mean[q] = sm * (1.f/256.f);
    rstd[q] = rsqrtf(ss * (1.f/256.f) - mean[q]*mean[q] + 1e-5f);
  }
  char* const Sw = lds + w * 8192;   // wave-private [16][256] bf16 swz
  #pragma unroll
  for (int ct = 0; ct < 16; ++ct) {
    #pragma unroll
    for (int q = 0; q < 4; ++q) {
      const float vv = (tri[ct][q] - mean[q]) * rstd[q] * gr[ct] + br[ct];
      *reinterpret_cast<__hip_bfloat16*>(Sw + xad(lh*4 + q, (ct*16 + l15)*2)) =
          __float2bfloat16(vv);
    }
  }
  __syncthreads();     // (ordering safety; staging is wave-private)

  // ---- out = (LN(tri) @ Wo^T) * sigmoid(x @ Wg^T), g recomputed, same C-layout
  const int rtg = h*8 + w;           // wave's global row-tile of x / out
  const size_t ob = (size_t)s * 65536 + (size_t)(h*128 + w*16) * 256;
  #pragma unroll
  for (int cg = 0; cg < 4; ++cg) {
    f32x4 ga[4], oa[4];
    #pragma unroll
    for (int j = 0; j < 4; ++j) { ga[j] = (f32x4){0.f,0.f,0.f,0.f}; oa[j] = (f32x4){0.f,0.f,0.f,0.f}; }
    #pragma unroll
    for (int ks = 0; ks < 8; ++ks) {
      const s16x8 Ax  = *reinterpret_cast<const s16x8*>(xs + (((size_t)rtg*8 + ks)*64 + lane)*8);
      const s16x8 Aln = *reinterpret_cast<const s16x8*>(Sw + xad(l15, ks*64 + lh*16));
      #pragma unroll
      for (int j = 0; j < 4; ++j) {
        const int ct = cg*4 + j;
        const s16x8 Bg = *reinterpret_cast<const s16x8*>(wg + (((size_t)ct*8 + ks)*64 + lane)*8);
        const s16x8 Bo = *reinterpret_cast<const s16x8*>(wo + (((size_t)ct*8 + ks)*64 + lane)*8);
        ga[j] = MFMA16(Ax,  Bg, ga[j]);
        oa[j] = MFMA16(Aln, Bo, oa[j]);
      }
    }
    #pragma unroll
    for (int j = 0; j < 4; ++j) {
      const int ct = cg*4 + j;
      #pragma unroll
      for (int q = 0; q < 4; ++q)
        out[ob + (size_t)(lh*4 + q)*256 + ct*16 + l15] = oa[j][q] * sigm(ga[j][q]);
    }
  }
}

extern "C" void kernel_launch(void* const* d_in, const int* in_sizes, int n_in,
                              void* d_out, int out_size, void* d_ws, size_t ws_size,
                              hipStream_t stream) {
  const float* pair   = (const float*)d_in[0];
  const float* w_in   = (const float*)d_in[1];
  const float* w_gate = (const float*)d_in[2];
  const float* w_out  = (const float*)d_in[3];
  const float* gamma  = (const float*)d_in[4];
  const float* beta   = (const float*)d_in[5];
  float* out = (float*)d_out;

  __hip_bfloat16* wfrag = (__hip_bfloat16*)d_ws;                    // 512 KB
  __hip_bfloat16* xws   = (__hip_bfloat16*)((char*)d_ws + 524288);  // 64 MB

  (void)in_sizes; (void)n_in; (void)out_size; (void)ws_size;

  wfrag_kernel<<<dim3(128, 4), 64, 0, stream>>>(w_in, w_gate, w_out, wfrag);
  ln_kernel<<<8192, 256, 0, stream>>>(pair, gamma, beta, xws);
  tri_fused<<<1024, 512, 0, stream>>>(xws, wfrag, gamma, beta, out);
}

// Round 3
// 228.740 us; speedup vs baseline: 2.2161x; 2.0433x over previous
//
#include <hip/hip_runtime.h>
#include <hip/hip_bf16.h>

typedef __attribute__((ext_vector_type(4))) float  f32x4;
typedef __attribute__((ext_vector_type(8))) short  s16x8;
typedef __attribute__((ext_vector_type(4))) short  s16x4;

union BH4 { s16x4 v; __hip_bfloat16 h[4]; };
union BH8 { s16x8 v; __hip_bfloat16 h[8]; };

#define MFMA16(A,B,C) __builtin_amdgcn_mfma_f32_16x16x32_bf16((A),(B),(C),0,0,0)

__device__ __forceinline__ float sigm(float x) { return 1.0f / (1.0f + __expf(-x)); }

// [rows][256] bf16 (512 B rows): XOR row into 16B slot (bank-conflict fix)
__device__ __forceinline__ int xad(int r, int byteInRow) {
  return ((r << 9) + byteInRow) ^ ((r & 7) << 4);
}
// chunk buffers: [rows][64] bf16 (128 B rows): slot16 ^= (i&7)
__device__ __forceinline__ int cad64(int i, int k) {   // k = bf16 idx 0..63
  return (i << 7) + ((((k >> 3) ^ (i & 7)) << 4) | ((k & 7) << 1));
}

// fp32 weight [256][256] -> bf16 MFMA B-fragment order:
// dst[((ct*8+ks)*64+lane)*8 + j] = w[ct*16 + (lane&15)][ks*32 + (lane>>4)*8 + j]
__global__ void wfrag_kernel(const float* __restrict__ w_in,
                             const float* __restrict__ w_gate,
                             const float* __restrict__ w_out,
                             __hip_bfloat16* __restrict__ dst) {
  const int lane = threadIdx.x;         // 64
  const int fid  = blockIdx.x;          // 0..127 = ct*8+ks
  const int m    = blockIdx.y;          // 0:wa 1:wb 2:wg 3:wo
  const float* src = (m == 0) ? w_in : (m == 1) ? (w_in + 65536)
                    : (m == 2) ? w_gate : w_out;
  const int e  = (fid >> 3) * 16 + (lane & 15);
  const int d0 = (fid & 7) * 32 + (lane >> 4) * 8;
  BH8 u;
  #pragma unroll
  for (int j = 0; j < 8; ++j) u.h[j] = __float2bfloat16(src[e * 256 + d0 + j]);
  *reinterpret_cast<s16x8*>(dst + (size_t)m * 65536 + ((size_t)fid * 64 + lane) * 8) = u.v;
}

// K1: x = LN(pair) -> xws in A-fragment order:
// xws[((s*16+rt)*8+ks)*512 + lane*8 + j] = x[s][rt*16 + (lane&15)][ks*32 + (lane>>4)*8 + j]
__global__ __launch_bounds__(256) void ln_kernel(
    const float* __restrict__ pair, const float* __restrict__ gamma,
    const float* __restrict__ beta, __hip_bfloat16* __restrict__ xws)
{
  __shared__ char Xl[8192];
  const int t  = threadIdx.x;
  const int s  = blockIdx.x >> 4;
  const int rt = blockIdx.x & 15;
  const int r  = t >> 4;                 // local row 0..15
  const int c0 = (t & 15) * 16;
  const float* src = pair + (((size_t)s * 256 + rt * 16 + r) * 256 + c0);
  float v[16];
  #pragma unroll
  for (int i = 0; i < 4; ++i) {
    const float4 f = *reinterpret_cast<const float4*>(src + i * 4);
    v[i*4+0]=f.x; v[i*4+1]=f.y; v[i*4+2]=f.z; v[i*4+3]=f.w;
  }
  float sm = 0.f, ss = 0.f;
  #pragma unroll
  for (int i = 0; i < 16; ++i) { sm += v[i]; ss += v[i]*v[i]; }
  #pragma unroll
  for (int m = 1; m < 16; m <<= 1) { sm += __shfl_xor(sm, m); ss += __shfl_xor(ss, m); }
  const float mean = sm * (1.f/256.f);
  const float rstd = rsqrtf(ss * (1.f/256.f) - mean*mean + 1e-5f);
  #pragma unroll
  for (int i = 0; i < 4; ++i) {
    const float4 gm = *reinterpret_cast<const float4*>(gamma + c0 + i*4);
    const float4 bt = *reinterpret_cast<const float4*>(beta  + c0 + i*4);
    BH4 o;
    o.h[0] = __float2bfloat16((v[i*4+0]-mean)*rstd*gm.x + bt.x);
    o.h[1] = __float2bfloat16((v[i*4+1]-mean)*rstd*gm.y + bt.y);
    o.h[2] = __float2bfloat16((v[i*4+2]-mean)*rstd*gm.z + bt.z);
    o.h[3] = __float2bfloat16((v[i*4+3]-mean)*rstd*gm.w + bt.w);
    *reinterpret_cast<s16x4*>(Xl + xad(r, (c0 + i*4)*2)) = o.v;
  }
  __syncthreads();
  #pragma unroll
  for (int p = 0; p < 2; ++p) {
    const int u  = t + p * 256;
    const int ks = u >> 6;
    const int lp = u & 63;
    const s16x8 f = *reinterpret_cast<const s16x8*>(
        Xl + xad(lp & 15, ks*64 + ((lp>>4)&3)*16));
    *reinterpret_cast<s16x8*>(xws + ((((size_t)s*16 + rt)*8 + ks)*64 + lp)*8) = f;
  }
}

// K2: block = half-slice (128 tri rows). 8 waves, 512 thr, 80 KB LDS, <=128 VGPR.
__global__ __launch_bounds__(512, 2) void tri_fused(
    const __hip_bfloat16* __restrict__ xws,
    const __hip_bfloat16* __restrict__ wfrag,
    const float* __restrict__ gamma, const float* __restrict__ beta,
    float* __restrict__ out)
{
  extern __shared__ __align__(16) char lds[];
  char* const XS = lds;            // 32768 B : x-chunk frags (linear, 4 rt x 8 ks)
  char* const AC = lds + 32768;    // 16384 B : a^T chunk [128 i][64 k] swz
  char* const BC = lds + 49152;    // 32768 B : b^T chunk [256 j][64 k] swz
  char* const SW = lds;            // 65536 B : ln(tri) [128 i][256 j] bf16 (reuse)

  const int raw = blockIdx.x;                 // 1024 blocks
  const int xcd = raw & 7, o = raw >> 3;
  const int s   = xcd * 64 + (o >> 1);        // slice 0..511 (siblings same XCD)
  const int h   = o & 1;                      // half: tri rows h*128..h*128+127

  const int tid = threadIdx.x, lane = tid & 63, w = tid >> 6;   // 8 waves
  const int l15 = lane & 15, lh = lane >> 4;                    // lh 0..3

  const __hip_bfloat16* const wa = wfrag;
  const __hip_bfloat16* const wb = wfrag + 65536;
  const __hip_bfloat16* const wg = wfrag + 131072;
  const __hip_bfloat16* const wo = wfrag + 196608;
  const __hip_bfloat16* const xs = xws + (size_t)s * 65536;

  f32x4 tri[16];
  #pragma unroll
  for (int jt = 0; jt < 16; ++jt) tri[jt] = (f32x4){0.f,0.f,0.f,0.f};

  // ---- prologue: stage x-chunk 0 (k-rows 0..63 = x row-tiles 0..3) into XS
  {
    s16x8 st[4];
    #pragma unroll
    for (int p = 0; p < 4; ++p)
      st[p] = *reinterpret_cast<const s16x8*>(xs + p*4096 + tid*8);
    #pragma unroll
    for (int p = 0; p < 4; ++p)
      *reinterpret_cast<s16x8*>(XS + p*8192 + tid*16) = st[p];
  }
  __syncthreads();

  for (int c = 0; c < 4; ++c) {
    // ---- phase A: a-GEMM for this wave's a-col tile (global ct = h*8+w)
    {
      const int ct = h*8 + w;
      f32x4 acc[4];
      #pragma unroll
      for (int rt = 0; rt < 4; ++rt) acc[rt] = (f32x4){0.f,0.f,0.f,0.f};
      #pragma unroll
      for (int ks = 0; ks < 8; ++ks) {
        const s16x8 Bf = *reinterpret_cast<const s16x8*>(wa + (((size_t)ct*8 + ks)*64 + lane)*8);
        #pragma unroll
        for (int rt = 0; rt < 4; ++rt) {
          const s16x8 Af = *reinterpret_cast<const s16x8*>(XS + ((rt*8 + ks)*64 + lane)*16);
          acc[rt] = MFMA16(Af, Bf, acc[rt]);
        }
      }
      #pragma unroll
      for (int rt = 0; rt < 4; ++rt) {
        const f32x4 vv = acc[rt];
        BH4 ov;
        #pragma unroll
        for (int q = 0; q < 4; ++q) ov.h[q] = __float2bfloat16(vv[q] * sigm(vv[q]));
        *reinterpret_cast<s16x4*>(AC + cad64(w*16 + l15, rt*16 + lh*4)) = ov.v;
      }
    }
    // ---- phases B0,B1: b-GEMM for ct = 2w, 2w+1 (all 16 covered by 8 waves)
    #pragma unroll
    for (int t = 0; t < 2; ++t) {
      const int ct = 2*w + t;
      f32x4 acc[4];
      #pragma unroll
      for (int rt = 0; rt < 4; ++rt) acc[rt] = (f32x4){0.f,0.f,0.f,0.f};
      #pragma unroll
      for (int ks = 0; ks < 8; ++ks) {
        const s16x8 Bf = *reinterpret_cast<const s16x8*>(wb + (((size_t)ct*8 + ks)*64 + lane)*8);
        #pragma unroll
        for (int rt = 0; rt < 4; ++rt) {
          const s16x8 Af = *reinterpret_cast<const s16x8*>(XS + ((rt*8 + ks)*64 + lane)*16);
          acc[rt] = MFMA16(Af, Bf, acc[rt]);
        }
      }
      #pragma unroll
      for (int rt = 0; rt < 4; ++rt) {
        const f32x4 vv = acc[rt];
        BH4 ov;
        #pragma unroll
        for (int q = 0; q < 4; ++q) ov.h[q] = __float2bfloat16(vv[q] * sigm(vv[q]));
        *reinterpret_cast<s16x4*>(BC + cad64(ct*16 + l15, rt*16 + lh*4)) = ov.v;
      }
    }
    __syncthreads();   // chunk bufs ready; all XS reads of chunk c done

    // issue next chunk's staging loads early (hide under tri accum)
    s16x8 st[4];
    if (c < 3) {
      #pragma unroll
      for (int p = 0; p < 4; ++p)
        st[p] = *reinterpret_cast<const s16x8*>(xs + (c+1)*16384 + p*4096 + tid*8);
    }
    // ---- tri accumulation: tri[i][j] += sum_k aT[i][k] bT[j][k] (K=64)
    #pragma unroll
    for (int kss = 0; kss < 2; ++kss) {
      const s16x8 ta = *reinterpret_cast<const s16x8*>(AC + cad64(w*16 + l15, kss*32 + lh*8));
      #pragma unroll
      for (int jt = 0; jt < 16; ++jt) {
        const s16x8 tb = *reinterpret_cast<const s16x8*>(BC + cad64(jt*16 + l15, kss*32 + lh*8));
        tri[jt] = MFMA16(ta, tb, tri[jt]);
      }
    }
    if (c < 3) {
      #pragma unroll
      for (int p = 0; p < 4; ++p)
        *reinterpret_cast<s16x8*>(XS + p*8192 + tid*16) = st[p];
    }
    __syncthreads();   // staging visible + tri reads done before next overwrite
  }

  // ---- LN(tri) in-wave; stage ln(tri) bf16 into SW (reuses all chunk LDS)
  {
    float mean[4], rstd[4];
    #pragma unroll
    for (int q = 0; q < 4; ++q) {
      float sm = 0.f, ss = 0.f;
      #pragma unroll
      for (int jt = 0; jt < 16; ++jt) { const float x = tri[jt][q]; sm += x; ss += x*x; }
      #pragma unroll
      for (int m = 1; m < 16; m <<= 1) { sm += __shfl_xor(sm, m); ss += __shfl_xor(ss, m); }
      mean[q] = sm * (1.f/256.f);
      rstd[q] = rsqrtf(ss * (1.f/256.f) - mean[q]*mean[q] + 1e-5f);
    }
    #pragma unroll
    for (int jt = 0; jt < 16; ++jt) {
      const float gm = gamma[jt*16 + l15];
      const float bt = beta [jt*16 + l15];
      #pragma unroll
      for (int q = 0; q < 4; ++q) {
        const float vv = (tri[jt][q] - mean[q]) * rstd[q] * gm + bt;
        *reinterpret_cast<__hip_bfloat16*>(
            SW + xad(w*16 + lh*4 + q, (jt*16 + l15)*2)) = __float2bfloat16(vv);
      }
    }
  }
  __syncthreads();

  // ---- out = (LN(tri) @ Wo^T) * sigmoid(x @ Wg^T); wave owns cols ct=2w,2w+1
  #pragma unroll
  for (int half = 0; half < 2; ++half) {
    #pragma unroll
    for (int t = 0; t < 2; ++t) {
      const int ct = 2*w + t;
      f32x4 og[4], oo[4];
      #pragma unroll
      for (int rt = 0; rt < 4; ++rt) { og[rt] = (f32x4){0.f,0.f,0.f,0.f}; oo[rt] = (f32x4){0.f,0.f,0.f,0.f}; }
      #pragma unroll
      for (int ks = 0; ks < 8; ++ks) {
        const s16x8 Bg = *reinterpret_cast<const s16x8*>(wg + (((size_t)ct*8 + ks)*64 + lane)*8);
        const s16x8 Bo = *reinterpret_cast<const s16x8*>(wo + (((size_t)ct*8 + ks)*64 + lane)*8);
        #pragma unroll
        for (int rt = 0; rt < 4; ++rt) {
          const int rtg = h*8 + half*4 + rt;   // global x row-tile
          const s16x8 Ax  = *reinterpret_cast<const s16x8*>(xs + (((size_t)rtg*8 + ks)*64 + lane)*8);
          const s16x8 Aln = *reinterpret_cast<const s16x8*>(
              SW + xad(half*64 + rt*16 + l15, ks*64 + lh*16));
          og[rt] = MFMA16(Ax,  Bg, og[rt]);
          oo[rt] = MFMA16(Aln, Bo, oo[rt]);
        }
      }
      #pragma unroll
      for (int rt = 0; rt < 4; ++rt) {
        #pragma unroll
        for (int q = 0; q < 4; ++q) {
          const int row = h*128 + half*64 + rt*16 + lh*4 + q;
          out[(size_t)s*65536 + (size_t)row*256 + ct*16 + l15] =
              oo[rt][q] * sigm(og[rt][q]);
        }
      }
    }
  }
}

extern "C" void kernel_launch(void* const* d_in, const int* in_sizes, int n_in,
                              void* d_out, int out_size, void* d_ws, size_t ws_size,
                              hipStream_t stream) {
  const float* pair   = (const float*)d_in[0];
  const float* w_in   = (const float*)d_in[1];
  const float* w_gate = (const float*)d_in[2];
  const float* w_out  = (const float*)d_in[3];
  const float* gamma  = (const float*)d_in[4];
  const float* beta   = (const float*)d_in[5];
  float* out = (float*)d_out;

  __hip_bfloat16* wfrag = (__hip_bfloat16*)d_ws;                    // 512 KB
  __hip_bfloat16* xws   = (__hip_bfloat16*)((char*)d_ws + 524288);  // 67 MB

  (void)in_sizes; (void)n_in; (void)out_size; (void)ws_size;

  hipFuncSetAttribute(reinterpret_cast<const void*>(tri_fused),
                      hipFuncAttributeMaxDynamicSharedMemorySize, 81920);

  wfrag_kernel<<<dim3(128, 4), 64, 0, stream>>>(w_in, w_gate, w_out, wfrag);
  ln_kernel<<<8192, 256, 0, stream>>>(pair, gamma, beta, xws);
  tri_fused<<<1024, 512, 81920, stream>>>(xws, wfrag, gamma, beta, out);
}